// Round 2
// baseline (9768.880 us; speedup 1.0000x reference)
//
#include <hip/hip_runtime.h>
#include <cstddef>

#define F 128
#define H 512
#define RB 32          // rows per tile; 128 tiles x 2 CUs = 256 blocks (1/CU)
#define NSTEPS 100
#define W1S 136        // W1t row stride (ushort, 16B-aligned)
#define ABS 136        // abuf row stride
#define H1S 520        // h1buf row stride (full 512 cols)
#define H2S 264        // h2buf row stride (256-col half)
#define W3S 264        // w3lds row stride (256-k half)
#define OUTS 132       // f32 out-staging stride

// ws layout: weights 794,624 B | exch 8 MB | flags 32 KB  (~9.2 MB total)
#define EXCH_OFF   794624
#define FLAGS_OFF  (EXCH_OFF + 8u*1024u*1024u)

typedef short short8 __attribute__((ext_vector_type(8)));
typedef float f32x4  __attribute__((ext_vector_type(4)));

__device__ __forceinline__ unsigned short f2bf(float f) {
    union { float f; unsigned int u; } v; v.f = f;
    unsigned int u = v.u;
    return (unsigned short)((u + 0x7FFFu + ((u >> 16) & 1u)) >> 16);  // RTNE
}
__device__ __forceinline__ float bf2f(unsigned short h) {
    union { unsigned int u; float f; } v; v.u = ((unsigned int)h) << 16;
    return v.f;
}
__device__ __forceinline__ float silu_f(float v) {
    float e = __expf(-v);
    return v * __builtin_amdgcn_rcpf(1.0f + e);
}

// ---- prep: transpose weights to bf16 B^T layout in workspace; zero flags --
__global__ void prep_weights(const float* __restrict__ W1,
                             const float* __restrict__ W2,
                             const float* __restrict__ W3,
                             unsigned short* __restrict__ ws,
                             int* __restrict__ flags) {
    unsigned short* W1t = ws;
    unsigned short* W2t = ws + 512 * W1S;
    unsigned short* W3t = W2t + 512 * 512;
    int stride = gridDim.x * blockDim.x;
    int t0 = blockIdx.x * blockDim.x + threadIdx.x;
    for (int i = t0; i < 512 * W1S; i += stride) {
        int n = i / W1S, k = i - n * W1S;
        W1t[i] = (k < 129) ? f2bf(W1[k * 512 + n]) : (unsigned short)0;
    }
    for (int i = t0; i < 512 * 512; i += stride) {
        int n = i >> 9, k = i & 511;
        W2t[i] = f2bf(W2[k * 512 + n]);
    }
    for (int i = t0; i < 128 * 512; i += stride) {
        int c = i >> 9, k = i & 511;
        W3t[i] = f2bf(W3[k * 128 + c]);
    }
    for (int i = t0; i < 256 * 32; i += stride) flags[i] = 0;
}

// ---- main kernel: CU pairs, fully weight-resident --------------------------
// block b: tile = b&127 (rows tile*32..+32), half = b>>7 (W2/h2 n-columns
// [half*256, half*256+256), W3 k-rows same range).
// Per wave (8 waves): w2f[2][16]=128 VGPR (its 32 n-cols of the half),
// w1f[4][4]=64 VGPR (its 64 h1 cols of all 512), W3-half in LDS.
// Per eval: both CUs compute full h1; each computes its h2 half and its
// layer-3 K-partial; 16 KB f32 partial exchanged via ws + flag handshake.
__global__ __launch_bounds__(512, 2) void ode_kernel(
    const float* __restrict__ x_in,
    const float* __restrict__ b1,
    const float* __restrict__ b2,
    const float* __restrict__ b3,
    const unsigned short* __restrict__ ws,
    float* __restrict__ exch,
    int* __restrict__ flags,
    float* __restrict__ traj) {

    __shared__ __attribute__((aligned(16))) unsigned short h1buf[RB * H1S]; // 33,280 B (reused as f32 out-stage)
    __shared__ __attribute__((aligned(16))) unsigned short h2buf[RB * H2S]; // 16,896 B
    __shared__ __attribute__((aligned(16))) unsigned short abuf[RB * ABS];  //  8,704 B
    __shared__ __attribute__((aligned(16))) unsigned short w3lds[128 * W3S];// 67,584 B

    const unsigned short* W1t = ws;
    const unsigned short* W2t = ws + 512 * W1S;
    const unsigned short* W3t = W2t + 512 * 512;

    const int b    = blockIdx.x;
    const int tile = b & 127;
    const int half = b >> 7;
    const int tid  = threadIdx.x;
    const int wave = tid >> 6;          // 0..7
    const int lane = tid & 63;
    const int l15  = lane & 15;
    const int q    = lane >> 4;         // 0..3
    const int rowbase = tile * RB;

    // ---- stage W3 K-half into LDS: w3lds[c][kk] = W3t[c][half*256+kk] ----
    for (int i = tid * 8; i < 128 * 256; i += 512 * 8) {
        int c = i >> 8, kk = i & 255;
        *(short8*)(w3lds + c * W3S + kk) =
            *(const short8*)(W3t + c * 512 + half * 256 + kk);
    }

    // ---- layer-1 weights (full): wave owns 64 h1-cols ----
    const int ncol1 = wave * 64 + l15;
    short8 w1f[4][4];
    float  b1v[4], t1v[4];
#pragma unroll
    for (int nt = 0; nt < 4; ++nt) {
        const unsigned short* wrow = W1t + (ncol1 + nt * 16) * W1S;
#pragma unroll
        for (int kt = 0; kt < 4; ++kt)
            w1f[nt][kt] = *(const short8*)(wrow + kt * 32 + q * 8);
        t1v[nt] = bf2f(wrow[128]);
        b1v[nt] = b1[ncol1 + nt * 16];
    }

    // ---- W2 half resident: wave owns 32 n-cols of [half*256, +256) ----
    const int n2 = half * 256 + wave * 32 + l15;
    short8 w2f[2][16];
    float  b2v[2];
#pragma unroll
    for (int nt = 0; nt < 2; ++nt) {
        const unsigned short* wb = W2t + (size_t)(n2 + nt * 16) * 512 + q * 8;
#pragma unroll
        for (int kt = 0; kt < 16; ++kt)
            w2f[nt][kt] = *(const short8*)(wb + kt * 32);
        b2v[nt] = b2[n2 + nt * 16];
    }
    // pin: define values via asm so RA cannot rematerialize the loads
#pragma unroll
    for (int nt = 0; nt < 2; ++nt)
#pragma unroll
        for (int kt = 0; kt < 16; ++kt)
            asm volatile("" : "+v"(w2f[nt][kt]));
#pragma unroll
    for (int nt = 0; nt < 4; ++nt)
#pragma unroll
        for (int kt = 0; kt < 4; ++kt)
            asm volatile("" : "+v"(w1f[nt][kt]));

    const int cown = wave * 16 + l15;   // layer-3 output column
    const float b3v = b3[cown];

    int* myflag = flags + b * 32;
    int* pflag  = flags + (b ^ 128) * 32;

    float xreg[2][4], accreg[2][4];

    // phase 0: load x, fill abuf, emit traj[0] (rows split by half)
#pragma unroll
    for (int m = 0; m < 2; ++m)
#pragma unroll
        for (int i = 0; i < 4; ++i) {
            int r = m * 16 + q * 4 + i;
            float v = x_in[(rowbase + r) * F + cown];
            xreg[m][i] = v;
            accreg[m][i] = 0.f;
            abuf[r * ABS + cown] = f2bf(v);
            if (m == half) traj[(rowbase + r) * F + cown] = v;
        }
    __syncthreads();

#pragma unroll 1
    for (int s = 0; s < NSTEPS - 1; ++s) {
        const float t0  = (float)s * (1.0f / 99.0f);
        const float tn  = (float)(s + 1) * (1.0f / 99.0f);
        const float dt  = tn - t0;
        const float hlf = 0.5f * dt;
        const float c16 = dt * (1.0f / 6.0f);
        const float c13 = dt * (1.0f / 3.0f);

#pragma unroll 1
        for (int e = 0; e < 4; ++e) {
            const float te = (e == 0) ? t0 : ((e == 3) ? tn : (t0 + hlf));
            const int cnt = s * 4 + e + 1;

            // ---- layer 1: full h1 = silu([x,t] @ W1 + b1), K=128 ----
#pragma unroll
            for (int m = 0; m < 2; ++m) {
                short8 af[4];
#pragma unroll
                for (int kt = 0; kt < 4; ++kt)
                    af[kt] = *(const short8*)(abuf + (m * 16 + l15) * ABS + kt * 32 + q * 8);
#pragma unroll
                for (int nt = 0; nt < 4; ++nt) {
                    f32x4 a = {0.f, 0.f, 0.f, 0.f};
#pragma unroll
                    for (int kt = 0; kt < 4; ++kt)
                        a = __builtin_amdgcn_mfma_f32_16x16x32_bf16(af[kt], w1f[nt][kt], a, 0, 0, 0);
                    const float bb = b1v[nt] + te * t1v[nt];
                    const int n = ncol1 + nt * 16;
#pragma unroll
                    for (int i = 0; i < 4; ++i)
                        h1buf[(m * 16 + q * 4 + i) * H1S + n] = f2bf(silu_f(a[i] + bb));
                }
            }
            __syncthreads();

            // ---- layer 2: own h2 half, K=512, W2 half in registers ----
#pragma unroll
            for (int m = 0; m < 2; ++m) {
                f32x4 acc0 = {0.f, 0.f, 0.f, 0.f};
                f32x4 acc1 = {0.f, 0.f, 0.f, 0.f};
#pragma unroll
                for (int kt = 0; kt < 16; ++kt) {
                    short8 a2 = *(const short8*)(h1buf + (m * 16 + l15) * H1S + kt * 32 + q * 8);
                    acc0 = __builtin_amdgcn_mfma_f32_16x16x32_bf16(a2, w2f[0][kt], acc0, 0, 0, 0);
                    acc1 = __builtin_amdgcn_mfma_f32_16x16x32_bf16(a2, w2f[1][kt], acc1, 0, 0, 0);
                }
                const int nl = wave * 32 + l15;
#pragma unroll
                for (int i = 0; i < 4; ++i) {
                    h2buf[(m * 16 + q * 4 + i) * H2S + nl]      = f2bf(silu_f(acc0[i] + b2v[0]));
                    h2buf[(m * 16 + q * 4 + i) * H2S + nl + 16] = f2bf(silu_f(acc1[i] + b2v[1]));
                }
            }
            __syncthreads();

            // ---- layer 3 partial: kP = h2_half @ W3[khalf,:] ----
            f32x4 a3[2];
#pragma unroll
            for (int m = 0; m < 2; ++m) {
                a3[m] = (f32x4){0.f, 0.f, 0.f, 0.f};
#pragma unroll
                for (int kt = 0; kt < 8; ++kt) {
                    short8 af = *(const short8*)(h2buf + (m * 16 + l15) * H2S + kt * 32 + q * 8);
                    short8 wf = *(const short8*)(w3lds + cown * W3S + kt * 32 + q * 8);
                    a3[m] = __builtin_amdgcn_mfma_f32_16x16x32_bf16(af, wf, a3[m], 0, 0, 0);
                }
            }
            // publish partial (parity double-buffered)
            float* slot = exch + (size_t)(((tile * 2 + half) * 2) + (cnt & 1)) * (RB * F);
#pragma unroll
            for (int m = 0; m < 2; ++m)
#pragma unroll
                for (int i = 0; i < 4; ++i)
                    slot[(m * 16 + q * 4 + i) * F + cown] = a3[m][i];
            __syncthreads();   // all partial stores drained (vmcnt) before flag
            if (tid == 0) {
                __hip_atomic_store(myflag, cnt, __ATOMIC_RELEASE, __HIP_MEMORY_SCOPE_AGENT);
                while (__hip_atomic_load(pflag, __ATOMIC_ACQUIRE, __HIP_MEMORY_SCOPE_AGENT) < cnt)
                    __builtin_amdgcn_s_sleep(1);
            }
            __syncthreads();

            // ---- combine partials, RK4 update ----
            const float* pslot = exch + (size_t)(((tile * 2 + (1 - half)) * 2) + (cnt & 1)) * (RB * F);
            float* outf = (float*)h1buf;   // h1buf dead until next eval's layer 1
#pragma unroll
            for (int m = 0; m < 2; ++m)
#pragma unroll
                for (int i = 0; i < 4; ++i) {
                    const int r = m * 16 + q * 4 + i;
                    const float kv = a3[m][i] + pslot[r * F + cown] + b3v;
                    if (e == 0) {
                        accreg[m][i] = xreg[m][i] + c16 * kv;
                        abuf[r * ABS + cown] = f2bf(xreg[m][i] + hlf * kv);
                    } else if (e == 1) {
                        accreg[m][i] += c13 * kv;
                        abuf[r * ABS + cown] = f2bf(xreg[m][i] + hlf * kv);
                    } else if (e == 2) {
                        accreg[m][i] += c13 * kv;
                        abuf[r * ABS + cown] = f2bf(xreg[m][i] + dt * kv);
                    } else {
                        float xn = accreg[m][i] + c16 * kv;
                        xreg[m][i] = xn;
                        abuf[r * ABS + cown] = f2bf(xn);
                        outf[r * OUTS + cown] = xn;
                    }
                }
            __syncthreads();

            // ---- coalesced traj store (rows split by half), f32x4/thread ----
            if (e == 3) {
                const int row = half * 16 + (tid >> 5);   // 16 rows x 32 thr
                const int c4  = (tid & 31) * 4;
                f32x4 v = *(const f32x4*)((const float*)h1buf + row * OUTS + c4);
                *(f32x4*)(traj + (size_t)(s + 1) * (4096 * F)
                               + (size_t)(rowbase + row) * F + c4) = v;
                __syncthreads();   // protect outf (=h1buf) from next layer 1
            }
        }
    }
}

extern "C" void kernel_launch(void* const* d_in, const int* in_sizes, int n_in,
                              void* d_out, int out_size, void* d_ws, size_t ws_size,
                              hipStream_t stream) {
    const float* x  = (const float*)d_in[0];
    const float* W1 = (const float*)d_in[1];
    const float* b1 = (const float*)d_in[2];
    const float* W2 = (const float*)d_in[3];
    const float* b2 = (const float*)d_in[4];
    const float* W3 = (const float*)d_in[5];
    const float* b3 = (const float*)d_in[6];
    // d_in[7] = n_steps (fixed at 100 per reference; hardcoded)

    unsigned short* wt = (unsigned short*)d_ws;                 // weights
    float* exch = (float*)((char*)d_ws + EXCH_OFF);             // 8 MB
    int*   flags = (int*)((char*)d_ws + FLAGS_OFF);             // 32 KB
    float* traj = (float*)d_out;

    prep_weights<<<256, 256, 0, stream>>>(W1, W2, W3, wt, flags);

    void* args[] = {(void*)&x, (void*)&b1, (void*)&b2, (void*)&b3,
                    (void*)&wt, (void*)&exch, (void*)&flags, (void*)&traj};
    hipLaunchCooperativeKernel((void*)ode_kernel, dim3(256), dim3(512),
                               args, 0, stream);
}

// Round 4
// 7119.190 us; speedup vs baseline: 1.3722x; 1.3722x over previous
//
#include <hip/hip_runtime.h>
#include <cstddef>

#define F 128
#define H 512
#define RB 16          // rows per block -> grid = 256 (one block per CU)
#define NSTEPS 100
#define W1S 136        // W1t row stride (ushort, 16B-aligned)
#define ABS 136        // abuf row stride
#define H1S 520        // h1 row stride (2-way max on ds_read_b128)
#define H2S 520        // h2 row stride
#define OUTS 132       // f32 out-staging stride

typedef short short8 __attribute__((ext_vector_type(8)));
typedef float f32x4  __attribute__((ext_vector_type(4)));
typedef __attribute__((address_space(1))) void glob_void;
typedef __attribute__((address_space(3))) void lds_void;

#define WAITVM(N) asm volatile("s_waitcnt vmcnt(" #N ")" ::: "memory")
#define WAITLG()  asm volatile("s_waitcnt lgkmcnt(0)" ::: "memory")

__device__ __forceinline__ unsigned short f2bf(float f) {
    union { float f; unsigned int u; } v; v.f = f;
    unsigned int u = v.u;
    return (unsigned short)((u + 0x7FFFu + ((u >> 16) & 1u)) >> 16);  // RTNE
}
__device__ __forceinline__ float bf2f(unsigned short h) {
    union { unsigned int u; float f; } v; v.u = ((unsigned int)h) << 16;
    return v.f;
}
__device__ __forceinline__ float silu_f(float v) {
    float e = __expf(-v);
    return v * __builtin_amdgcn_rcpf(1.0f + e);
}

// ---- prep: transpose weights to bf16 B^T layout in workspace -------------
__global__ void prep_weights(const float* __restrict__ W1,
                             const float* __restrict__ W2,
                             const float* __restrict__ W3,
                             unsigned short* __restrict__ ws) {
    unsigned short* W1t = ws;
    unsigned short* W2t = ws + 512 * W1S;
    unsigned short* W3t = W2t + 512 * 512;
    int stride = gridDim.x * blockDim.x;
    int t0 = blockIdx.x * blockDim.x + threadIdx.x;
    for (int i = t0; i < 512 * W1S; i += stride) {
        int n = i / W1S, k = i - n * W1S;
        W1t[i] = (k < 129) ? f2bf(W1[k * 512 + n]) : (unsigned short)0;
    }
    for (int i = t0; i < 512 * 512; i += stride) {
        int n = i >> 9, k = i & 511;
        W2t[i] = f2bf(W2[k * 512 + n]);
    }
    for (int i = t0; i < 128 * 512; i += stride) {
        int c = i >> 9, k = i & 511;
        W3t[i] = f2bf(W3[k * 128 + c]);
    }
}

// ---- main persistent kernel ----------------------------------------------
// 512 threads = 8 waves. Wave w owns h-cols [w*64,+64) in layers 1/2 and
// output cols [w*16,+16) in layer 3. W1/W3 + biases in registers.
// W2 streamed per eval via global_load_lds: 16 chunks of 32 KB (all 512 n,
// 32 k each), 3-deep LDS ring, counted vmcnt, no in-loop barriers (each
// wave stages exactly the rows it consumes -> wave-private, no cross-wave
// visibility needed). Slot-swizzled on the global source; matching XOR on
// the ds_read side. Traj stores are non-temporal (keeps W2 L2-resident)
// and coalesced via an f32 LDS tile.
__global__ __launch_bounds__(512, 2)
void ode_kernel(
    const float* __restrict__ x_in,
    const float* __restrict__ b1,
    const float* __restrict__ b2,
    const float* __restrict__ b3,
    const unsigned short* __restrict__ ws,
    float* __restrict__ traj) {

    __shared__ __attribute__((aligned(16))) unsigned short h1buf[RB * H1S];  // 16,640 B
    __shared__ __attribute__((aligned(16))) unsigned short h2buf[RB * H2S];  // 16,640 B
    __shared__ __attribute__((aligned(16))) unsigned short abuf[RB * ABS];   //  4,352 B
    __shared__ __attribute__((aligned(16))) float outbuf[RB * OUTS];         //  8,448 B
    __shared__ __attribute__((aligned(16))) unsigned short w2c[3 * 16384];   // 98,304 B

    const unsigned short* W1t = ws;
    const unsigned short* W2t = ws + 512 * W1S;
    const unsigned short* W3t = W2t + 512 * 512;

    const int tid  = threadIdx.x;
    const int wave = tid >> 6;          // 0..7
    const int lane = tid & 63;
    const int l15  = lane & 15;
    const int q    = lane >> 4;         // quad 0..3
    const int rowbase = blockIdx.x * RB;

    // ---- layer-1 weight fragments + biases (constant) ----
    const int ncol = wave * 64 + l15;   // layer1/2 n-col base for nt=0
    short8 w1f[4][4];
    float  b1v[4], t1v[4], b2v[4];
#pragma unroll
    for (int nt = 0; nt < 4; ++nt) {
        const unsigned short* wrow = W1t + (ncol + nt * 16) * W1S;
#pragma unroll
        for (int kt = 0; kt < 4; ++kt)
            w1f[nt][kt] = *(const short8*)(wrow + kt * 32 + q * 8);
        t1v[nt] = bf2f(wrow[128]);
        b1v[nt] = b1[ncol + nt * 16];
        b2v[nt] = b2[ncol + nt * 16];
    }
    const int cown = wave * 16 + l15;   // layer-3 output column
    short8 w3f[16];
    {
        const unsigned short* wrow = W3t + cown * 512;
#pragma unroll
        for (int kt = 0; kt < 16; ++kt)
            w3f[kt] = *(const short8*)(wrow + kt * 32 + q * 8);
    }
    const float b3v = b3[cown];

    // ---- W2 staging geometry -------------------------------------------
    // chunk c = k-slice [c*32, c*32+32), LDS layout: row n at ushort n*32,
    // slot s (16B) holds global k-part (s ^ (n&3) ^ ((n>>2)&3)).
    // Wave w stages rows [w*64, w*64+64) = exactly its consumption slice,
    // via 4 global_load_lds (64 lanes x 16 B, linear LDS dest = base+lane*16).
    const unsigned short* sbase[4];
    {
        const int mlan  = ((lane >> 2) & 3) ^ (lane >> 4);   // (n&3)^((n>>2)&3)
        const int partp = (lane & 3) ^ mlan;                 // pre-swizzled src part
#pragma unroll
        for (int j = 0; j < 4; ++j) {
            const int n = wave * 64 + j * 16 + (lane >> 2);
            sbase[j] = W2t + (size_t)n * 512 + partp * 8;
        }
    }
    int roff[4];   // consumer ds_read offsets within a chunk buf (ushort)
#pragma unroll
    for (int nt = 0; nt < 4; ++nt) {
        const int nr = wave * 64 + nt * 16 + l15;
        const int m  = (nr & 3) ^ ((nr >> 2) & 3);
        roff[nt] = nr * 32 + (q ^ m) * 8;
    }

#define ISSUE(c, b) do {                                                     \
    _Pragma("unroll")                                                        \
    for (int j_ = 0; j_ < 4; ++j_) {                                         \
        const unsigned short* srcp_ = sbase[j_] + (c) * 32;                  \
        unsigned short* dstp_ = w2c + (b) * 16384 + (wave * 4 + j_) * 512;   \
        __builtin_amdgcn_global_load_lds((const glob_void*)srcp_,            \
                                         (lds_void*)dstp_, 16, 0, 0);        \
    }                                                                        \
} while (0)

    float xreg[4];    // RK4 state: row q*4+i, col cown
    float accreg[4];

    // phase 0: load x, emit traj[0], fill abuf; pre-issue chunks 0..2
    ISSUE(0, 0); ISSUE(1, 1); ISSUE(2, 2);
#pragma unroll
    for (int i = 0; i < 4; ++i) {
        int r = q * 4 + i;
        float v = x_in[(rowbase + r) * F + cown];
        xreg[i] = v;
        __builtin_nontemporal_store(v, traj + (rowbase + r) * F + cown);
        abuf[r * ABS + cown] = f2bf(v);
    }
    __syncthreads();   // barrier drain lands chunks 0..2

#pragma unroll 1
    for (int s = 0; s < NSTEPS - 1; ++s) {
        const float t0  = (float)s * (1.0f / 99.0f);
        const float tn  = (float)(s + 1) * (1.0f / 99.0f);
        const float dt  = tn - t0;
        const float hlf = 0.5f * dt;
        const float c16 = dt * (1.0f / 6.0f);
        const float c13 = dt * (1.0f / 3.0f);

#pragma unroll 1
        for (int e = 0; e < 4; ++e) {
            const float te = (e == 0) ? t0 : ((e == 3) ? tn : (t0 + hlf));

            // ---- layer 1: h1 = silu([x,t] @ W1 + b1), K=128, regs ----
            {
                short8 af[4];
#pragma unroll
                for (int kt = 0; kt < 4; ++kt)
                    af[kt] = *(const short8*)(abuf + l15 * ABS + kt * 32 + q * 8);
#pragma unroll
                for (int nt = 0; nt < 4; ++nt) {
                    f32x4 a = {0.f, 0.f, 0.f, 0.f};
#pragma unroll
                    for (int kt = 0; kt < 4; ++kt)
                        a = __builtin_amdgcn_mfma_f32_16x16x32_bf16(af[kt], w1f[nt][kt], a, 0, 0, 0);
                    const float bb = b1v[nt] + te * t1v[nt];
                    const int n = ncol + nt * 16;
#pragma unroll
                    for (int i = 0; i < 4; ++i)
                        h1buf[(q * 4 + i) * H1S + n] = f2bf(silu_f(a[i] + bb));
                }
            }
            __syncthreads();   // h1 ready; also guarantees ring chunks landed

            // ---- layer 2: h2 = silu(h1 @ W2 + b2), K=512, DMA-streamed ----
            {
                f32x4 acc0 = {0.f, 0.f, 0.f, 0.f};
                f32x4 acc1 = {0.f, 0.f, 0.f, 0.f};
                f32x4 acc2 = {0.f, 0.f, 0.f, 0.f};
                f32x4 acc3 = {0.f, 0.f, 0.f, 0.f};
#pragma unroll 16
                for (int c = 0; c < 16; ++c) {
                    const int b = c % 3;
                    if (c >= 1) {
                        if (c <= 13)      WAITVM(8);
                        else if (c == 14) WAITVM(4);
                        else              WAITVM(0);
                    }
                    __builtin_amdgcn_sched_barrier(0);
                    short8 a2  = *(const short8*)(h1buf + l15 * H1S + c * 32 + q * 8);
                    short8 bf0 = *(const short8*)(w2c + b * 16384 + roff[0]);
                    short8 bf1 = *(const short8*)(w2c + b * 16384 + roff[1]);
                    short8 bf2 = *(const short8*)(w2c + b * 16384 + roff[2]);
                    short8 bf3 = *(const short8*)(w2c + b * 16384 + roff[3]);
                    acc0 = __builtin_amdgcn_mfma_f32_16x16x32_bf16(a2, bf0, acc0, 0, 0, 0);
                    acc1 = __builtin_amdgcn_mfma_f32_16x16x32_bf16(a2, bf1, acc1, 0, 0, 0);
                    acc2 = __builtin_amdgcn_mfma_f32_16x16x32_bf16(a2, bf2, acc2, 0, 0, 0);
                    acc3 = __builtin_amdgcn_mfma_f32_16x16x32_bf16(a2, bf3, acc3, 0, 0, 0);
                    WAITLG();                          // our ds_reads of buf b retired
                    __builtin_amdgcn_sched_barrier(0);
                    if (c + 3 < 16) ISSUE(c + 3, b);   // refill the ring slot
                }
                const f32x4 accs[4] = {acc0, acc1, acc2, acc3};
#pragma unroll
                for (int nt = 0; nt < 4; ++nt) {
                    const int n = ncol + nt * 16;
#pragma unroll
                    for (int i = 0; i < 4; ++i)
                        h2buf[(q * 4 + i) * H2S + n] = f2bf(silu_f(accs[nt][i] + b2v[nt]));
                }
            }
            __syncthreads();   // h2 ready; w2c fully consumed

            // pre-issue next eval's first 3 chunks (skip on the very last
            // eval: never reach endpgm with LDS-targeted DMA in flight)
            if (s != NSTEPS - 2 || e != 3) { ISSUE(0, 0); ISSUE(1, 1); ISSUE(2, 2); }

            // ---- layer 3: k = h2 @ W3 + b3 (weights in regs), then RK4 ----
            {
                f32x4 a3 = {0.f, 0.f, 0.f, 0.f};
#pragma unroll
                for (int kt = 0; kt < 16; ++kt) {
                    short8 af = *(const short8*)(h2buf + l15 * H2S + kt * 32 + q * 8);
                    a3 = __builtin_amdgcn_mfma_f32_16x16x32_bf16(af, w3f[kt], a3, 0, 0, 0);
                }
#pragma unroll
                for (int i = 0; i < 4; ++i) {
                    const int r = q * 4 + i;
                    const float kv = a3[i] + b3v;
                    if (e == 0) {
                        accreg[i] = xreg[i] + c16 * kv;
                        abuf[r * ABS + cown] = f2bf(xreg[i] + hlf * kv);
                    } else if (e == 1) {
                        accreg[i] += c13 * kv;
                        abuf[r * ABS + cown] = f2bf(xreg[i] + hlf * kv);
                    } else if (e == 2) {
                        accreg[i] += c13 * kv;
                        abuf[r * ABS + cown] = f2bf(xreg[i] + dt * kv);
                    } else {
                        float xn = accreg[i] + c16 * kv;
                        xreg[i] = xn;
                        abuf[r * ABS + cown] = f2bf(xn);
                        outbuf[r * OUTS + cown] = xn;   // f32 tile for coalesced NT store
                    }
                }
            }
            __syncthreads();

            // ---- non-temporal coalesced traj store, f32x4/thread ----
            if (e == 3) {
                const int row = tid >> 5;          // 16 rows x 32 threads
                const int c4  = (tid & 31) * 4;
                f32x4 v = *(const f32x4*)(outbuf + row * OUTS + c4);
                __builtin_nontemporal_store(v,
                    (f32x4*)(traj + (size_t)(s + 1) * (4096 * F)
                                  + (size_t)(rowbase + row) * F + c4));
            }
        }
    }
    // safety: drain any outstanding VMEM (incl. LDS-targeted DMA) before exit
    asm volatile("s_waitcnt vmcnt(0)" ::: "memory");
#undef ISSUE
}

extern "C" void kernel_launch(void* const* d_in, const int* in_sizes, int n_in,
                              void* d_out, int out_size, void* d_ws, size_t ws_size,
                              hipStream_t stream) {
    const float* x  = (const float*)d_in[0];
    const float* W1 = (const float*)d_in[1];
    const float* b1 = (const float*)d_in[2];
    const float* W2 = (const float*)d_in[3];
    const float* b2 = (const float*)d_in[4];
    const float* W3 = (const float*)d_in[5];
    const float* b3 = (const float*)d_in[6];
    // d_in[7] = n_steps (fixed at 100 per reference; hardcoded)

    unsigned short* wt = (unsigned short*)d_ws;  // needs 794,624 B
    float* traj = (float*)d_out;

    prep_weights<<<256, 256, 0, stream>>>(W1, W2, W3, wt);
    ode_kernel<<<4096 / RB, 512, 0, stream>>>(x, b1, b2, b3, wt, traj);
}

// Round 5
// 6725.414 us; speedup vs baseline: 1.4525x; 1.0586x over previous
//
#include <hip/hip_runtime.h>
#include <cstddef>

#define F 128
#define H 512
#define RB 16          // rows per block -> grid = 256 (one block per CU)
#define NSTEPS 100
#define W1S 136        // W1t row stride (ushort, 16B-aligned)
#define ABS 136        // abuf row stride
#define H1S 520        // h1 row stride (2-way max on ds_read_b128)
#define H2S 520        // h2 row stride
#define OUTS 132       // f32 out-staging stride

typedef short short8 __attribute__((ext_vector_type(8)));
typedef float f32x4  __attribute__((ext_vector_type(4)));
typedef __attribute__((address_space(1))) void glob_void;
typedef __attribute__((address_space(3))) void lds_void;

#define WAITVM(N) asm volatile("s_waitcnt vmcnt(" #N ")" ::: "memory")
#define WAITLG()  asm volatile("s_waitcnt lgkmcnt(0)" ::: "memory")

__device__ __forceinline__ unsigned short f2bf(float f) {
    union { float f; unsigned int u; } v; v.f = f;
    unsigned int u = v.u;
    return (unsigned short)((u + 0x7FFFu + ((u >> 16) & 1u)) >> 16);  // RTNE
}
__device__ __forceinline__ float bf2f(unsigned short h) {
    union { unsigned int u; float f; } v; v.u = ((unsigned int)h) << 16;
    return v.f;
}
__device__ __forceinline__ float silu_f(float v) {
    float e = __expf(-v);
    return v * __builtin_amdgcn_rcpf(1.0f + e);
}

// ---- prep: transpose weights to bf16 B^T layout in workspace -------------
__global__ void prep_weights(const float* __restrict__ W1,
                             const float* __restrict__ W2,
                             const float* __restrict__ W3,
                             unsigned short* __restrict__ ws) {
    unsigned short* W1t = ws;
    unsigned short* W2t = ws + 512 * W1S;
    unsigned short* W3t = W2t + 512 * 512;
    int stride = gridDim.x * blockDim.x;
    int t0 = blockIdx.x * blockDim.x + threadIdx.x;
    for (int i = t0; i < 512 * W1S; i += stride) {
        int n = i / W1S, k = i - n * W1S;
        W1t[i] = (k < 129) ? f2bf(W1[k * 512 + n]) : (unsigned short)0;
    }
    for (int i = t0; i < 512 * 512; i += stride) {
        int n = i >> 9, k = i & 511;
        W2t[i] = f2bf(W2[k * 512 + n]);
    }
    for (int i = t0; i < 128 * 512; i += stride) {
        int c = i >> 9, k = i & 511;
        W3t[i] = f2bf(W3[k * 128 + c]);
    }
}

// ---- main persistent kernel ----------------------------------------------
// 512 threads = 8 waves. Wave w owns h-cols [w*64,+64) in layers 1/2 and
// output cols [w*16,+16) in layer 3. W1/W3 + biases in registers (forced
// resident via waves_per_eu(2,2): LDS already caps occupancy at 2 waves/EU,
// so the RA may use up to 256 VGPRs -> no remat/spill of weight frags).
// W2 streamed per eval via global_load_lds: 16 chunks of 32 KB, 3-deep LDS
// ring, counted vmcnt, no in-loop barriers. Chunk order is ROTATED by a
// per-XCD phase so the 32 CUs of an XCD never request the same L2 lines
// simultaneously (L2 has no multicast; lockstep same-line reads serialize).
__global__ __launch_bounds__(512, 2) __attribute__((amdgpu_waves_per_eu(2, 2)))
void ode_kernel(
    const float* __restrict__ x_in,
    const float* __restrict__ b1,
    const float* __restrict__ b2,
    const float* __restrict__ b3,
    const unsigned short* __restrict__ ws,
    float* __restrict__ traj) {

    __shared__ __attribute__((aligned(16))) unsigned short h1buf[RB * H1S];  // 16,640 B
    __shared__ __attribute__((aligned(16))) unsigned short h2buf[RB * H2S];  // 16,640 B
    __shared__ __attribute__((aligned(16))) unsigned short abuf[RB * ABS];   //  4,352 B
    __shared__ __attribute__((aligned(16))) float outbuf[RB * OUTS];         //  8,448 B
    __shared__ __attribute__((aligned(16))) unsigned short w2c[3 * 16384];   // 98,304 B

    const unsigned short* W1t = ws;
    const unsigned short* W2t = ws + 512 * W1S;
    const unsigned short* W3t = W2t + 512 * 512;

    const int tid  = threadIdx.x;
    const int wave = tid >> 6;          // 0..7
    const int lane = tid & 63;
    const int l15  = lane & 15;
    const int q    = lane >> 4;         // quad 0..3
    const int rowbase = blockIdx.x * RB;
    // per-XCD desync phase: blocks round-robin XCDs by (b&7); the 32 blocks
    // of one XCD get phases 0..15 (x2) -> <=2 CUs touch a chunk at a time.
    const int phase = (blockIdx.x >> 3) & 15;
#define CC(c) (((c) + phase) & 15)

    // ---- layer-1 weight fragments + biases (constant) ----
    const int ncol = wave * 64 + l15;   // layer1/2 n-col base for nt=0
    short8 w1f[4][4];
    float  b1v[4], t1v[4], b2v[4];
#pragma unroll
    for (int nt = 0; nt < 4; ++nt) {
        const unsigned short* wrow = W1t + (ncol + nt * 16) * W1S;
#pragma unroll
        for (int kt = 0; kt < 4; ++kt)
            w1f[nt][kt] = *(const short8*)(wrow + kt * 32 + q * 8);
        t1v[nt] = bf2f(wrow[128]);
        b1v[nt] = b1[ncol + nt * 16];
        b2v[nt] = b2[ncol + nt * 16];
    }
    const int cown = wave * 16 + l15;   // layer-3 output column
    short8 w3f[16];
    {
        const unsigned short* wrow = W3t + cown * 512;
#pragma unroll
        for (int kt = 0; kt < 16; ++kt)
            w3f[kt] = *(const short8*)(wrow + kt * 32 + q * 8);
    }
    const float b3v = b3[cown];

    // ---- W2 staging geometry -------------------------------------------
    // chunk c = k-slice [c*32, c*32+32), LDS layout: row n at ushort n*32,
    // slot s (16B) holds global k-part (s ^ (n&3) ^ ((n>>2)&3)).
    // Wave w stages rows [w*64, w*64+64) = exactly its consumption slice,
    // via 4 global_load_lds (64 lanes x 16 B, linear LDS dest = base+lane*16).
    const unsigned short* sbase[4];
    {
        const int mlan  = ((lane >> 2) & 3) ^ (lane >> 4);   // (n&3)^((n>>2)&3)
        const int partp = (lane & 3) ^ mlan;                 // pre-swizzled src part
#pragma unroll
        for (int j = 0; j < 4; ++j) {
            const int n = wave * 64 + j * 16 + (lane >> 2);
            sbase[j] = W2t + (size_t)n * 512 + partp * 8;
        }
    }
    int roff[4];   // consumer ds_read offsets within a chunk buf (ushort)
#pragma unroll
    for (int nt = 0; nt < 4; ++nt) {
        const int nr = wave * 64 + nt * 16 + l15;
        const int m  = (nr & 3) ^ ((nr >> 2) & 3);
        roff[nt] = nr * 32 + (q ^ m) * 8;
    }

#define ISSUE(c, b) do {                                                     \
    _Pragma("unroll")                                                        \
    for (int j_ = 0; j_ < 4; ++j_) {                                         \
        const unsigned short* srcp_ = sbase[j_] + (c) * 32;                  \
        unsigned short* dstp_ = w2c + (b) * 16384 + (wave * 4 + j_) * 512;   \
        __builtin_amdgcn_global_load_lds((const glob_void*)srcp_,            \
                                         (lds_void*)dstp_, 16, 0, 0);        \
    }                                                                        \
} while (0)

    float xreg[4];    // RK4 state: row q*4+i, col cown
    float accreg[4];

    // phase 0: load x, emit traj[0], fill abuf; pre-issue chunks CC(0..2)
    ISSUE(CC(0), 0); ISSUE(CC(1), 1); ISSUE(CC(2), 2);
#pragma unroll
    for (int i = 0; i < 4; ++i) {
        int r = q * 4 + i;
        float v = x_in[(rowbase + r) * F + cown];
        xreg[i] = v;
        __builtin_nontemporal_store(v, traj + (rowbase + r) * F + cown);
        abuf[r * ABS + cown] = f2bf(v);
    }
    __syncthreads();   // barrier drain lands the pre-issued chunks

#pragma unroll 1
    for (int s = 0; s < NSTEPS - 1; ++s) {
        const float t0  = (float)s * (1.0f / 99.0f);
        const float tn  = (float)(s + 1) * (1.0f / 99.0f);
        const float dt  = tn - t0;
        const float hlf = 0.5f * dt;
        const float c16 = dt * (1.0f / 6.0f);
        const float c13 = dt * (1.0f / 3.0f);

#pragma unroll 1
        for (int e = 0; e < 4; ++e) {
            const float te = (e == 0) ? t0 : ((e == 3) ? tn : (t0 + hlf));

            // ---- layer 1: h1 = silu([x,t] @ W1 + b1), K=128, regs ----
            {
                short8 af[4];
#pragma unroll
                for (int kt = 0; kt < 4; ++kt)
                    af[kt] = *(const short8*)(abuf + l15 * ABS + kt * 32 + q * 8);
#pragma unroll
                for (int nt = 0; nt < 4; ++nt) {
                    f32x4 a = {0.f, 0.f, 0.f, 0.f};
#pragma unroll
                    for (int kt = 0; kt < 4; ++kt)
                        a = __builtin_amdgcn_mfma_f32_16x16x32_bf16(af[kt], w1f[nt][kt], a, 0, 0, 0);
                    const float bb = b1v[nt] + te * t1v[nt];
                    const int n = ncol + nt * 16;
#pragma unroll
                    for (int i = 0; i < 4; ++i)
                        h1buf[(q * 4 + i) * H1S + n] = f2bf(silu_f(a[i] + bb));
                }
            }
            __syncthreads();   // h1 ready; also guarantees ring chunks landed

            // ---- layer 2: h2 = silu(h1 @ W2 + b2), K=512, DMA-streamed ----
            {
                f32x4 acc0 = {0.f, 0.f, 0.f, 0.f};
                f32x4 acc1 = {0.f, 0.f, 0.f, 0.f};
                f32x4 acc2 = {0.f, 0.f, 0.f, 0.f};
                f32x4 acc3 = {0.f, 0.f, 0.f, 0.f};
#pragma unroll 16
                for (int c = 0; c < 16; ++c) {
                    const int b = c % 3;
                    const int cc = CC(c);
                    if (c >= 1) {
                        if (c <= 13)      WAITVM(8);
                        else if (c == 14) WAITVM(4);
                        else              WAITVM(0);
                    }
                    __builtin_amdgcn_sched_barrier(0);
                    short8 a2  = *(const short8*)(h1buf + l15 * H1S + cc * 32 + q * 8);
                    short8 bf0 = *(const short8*)(w2c + b * 16384 + roff[0]);
                    short8 bf1 = *(const short8*)(w2c + b * 16384 + roff[1]);
                    short8 bf2 = *(const short8*)(w2c + b * 16384 + roff[2]);
                    short8 bf3 = *(const short8*)(w2c + b * 16384 + roff[3]);
                    acc0 = __builtin_amdgcn_mfma_f32_16x16x32_bf16(a2, bf0, acc0, 0, 0, 0);
                    acc1 = __builtin_amdgcn_mfma_f32_16x16x32_bf16(a2, bf1, acc1, 0, 0, 0);
                    acc2 = __builtin_amdgcn_mfma_f32_16x16x32_bf16(a2, bf2, acc2, 0, 0, 0);
                    acc3 = __builtin_amdgcn_mfma_f32_16x16x32_bf16(a2, bf3, acc3, 0, 0, 0);
                    WAITLG();                          // our ds_reads of buf b retired
                    __builtin_amdgcn_sched_barrier(0);
                    if (c + 3 < 16) ISSUE(CC(c + 3), b);   // refill the ring slot
                }
                const f32x4 accs[4] = {acc0, acc1, acc2, acc3};
#pragma unroll
                for (int nt = 0; nt < 4; ++nt) {
                    const int n = ncol + nt * 16;
#pragma unroll
                    for (int i = 0; i < 4; ++i)
                        h2buf[(q * 4 + i) * H2S + n] = f2bf(silu_f(accs[nt][i] + b2v[nt]));
                }
            }
            __syncthreads();   // h2 ready; w2c fully consumed

            // pre-issue next eval's first 3 chunks (skip on the very last
            // eval: never reach endpgm with LDS-targeted DMA in flight)
            if (s != NSTEPS - 2 || e != 3) {
                ISSUE(CC(0), 0); ISSUE(CC(1), 1); ISSUE(CC(2), 2);
            }

            // ---- layer 3: k = h2 @ W3 + b3 (weights in regs), then RK4 ----
            {
                f32x4 a3 = {0.f, 0.f, 0.f, 0.f};
#pragma unroll
                for (int kt = 0; kt < 16; ++kt) {
                    short8 af = *(const short8*)(h2buf + l15 * H2S + kt * 32 + q * 8);
                    a3 = __builtin_amdgcn_mfma_f32_16x16x32_bf16(af, w3f[kt], a3, 0, 0, 0);
                }
#pragma unroll
                for (int i = 0; i < 4; ++i) {
                    const int r = q * 4 + i;
                    const float kv = a3[i] + b3v;
                    if (e == 0) {
                        accreg[i] = xreg[i] + c16 * kv;
                        abuf[r * ABS + cown] = f2bf(xreg[i] + hlf * kv);
                    } else if (e == 1) {
                        accreg[i] += c13 * kv;
                        abuf[r * ABS + cown] = f2bf(xreg[i] + hlf * kv);
                    } else if (e == 2) {
                        accreg[i] += c13 * kv;
                        abuf[r * ABS + cown] = f2bf(xreg[i] + dt * kv);
                    } else {
                        float xn = accreg[i] + c16 * kv;
                        xreg[i] = xn;
                        abuf[r * ABS + cown] = f2bf(xn);
                        outbuf[r * OUTS + cown] = xn;   // f32 tile for coalesced NT store
                    }
                }
            }
            __syncthreads();

            // ---- non-temporal coalesced traj store, f32x4/thread ----
            if (e == 3) {
                const int row = tid >> 5;          // 16 rows x 32 threads
                const int c4  = (tid & 31) * 4;
                f32x4 v = *(const f32x4*)(outbuf + row * OUTS + c4);
                __builtin_nontemporal_store(v,
                    (f32x4*)(traj + (size_t)(s + 1) * (4096 * F)
                                  + (size_t)(rowbase + row) * F + c4));
            }
        }
    }
    // safety: drain any outstanding VMEM (incl. LDS-targeted DMA) before exit
    asm volatile("s_waitcnt vmcnt(0)" ::: "memory");
#undef ISSUE
#undef CC
}

extern "C" void kernel_launch(void* const* d_in, const int* in_sizes, int n_in,
                              void* d_out, int out_size, void* d_ws, size_t ws_size,
                              hipStream_t stream) {
    const float* x  = (const float*)d_in[0];
    const float* W1 = (const float*)d_in[1];
    const float* b1 = (const float*)d_in[2];
    const float* W2 = (const float*)d_in[3];
    const float* b2 = (const float*)d_in[4];
    const float* W3 = (const float*)d_in[5];
    const float* b3 = (const float*)d_in[6];
    // d_in[7] = n_steps (fixed at 100 per reference; hardcoded)

    unsigned short* wt = (unsigned short*)d_ws;  // needs 794,624 B
    float* traj = (float*)d_out;

    prep_weights<<<256, 256, 0, stream>>>(W1, W2, W3, wt);
    ode_kernel<<<4096 / RB, 512, 0, stream>>>(x, b1, b2, b3, wt, traj);
}

// Round 6
// 5323.687 us; speedup vs baseline: 1.8350x; 1.2633x over previous
//
#include <hip/hip_runtime.h>
#include <cstddef>

#define F 128
#define H 512
#define RB 16          // rows per block -> grid = 256 (one block per CU)
#define NSTEPS 100
#define ABS 136        // abuf row stride (ushort)
#define H1S 520        // h1 row stride
#define H2S 520        // h2 row stride
#define OUTS 132       // f32 out-staging stride
#define W12S 640       // merged W1|W2 row stride (k: 0..127 W1, 128..639 W2)

typedef short short8 __attribute__((ext_vector_type(8)));
typedef float f32x4  __attribute__((ext_vector_type(4)));
typedef __attribute__((address_space(1))) void glob_void;
typedef __attribute__((address_space(3))) void lds_void;

#define WAITVM(N) asm volatile("s_waitcnt vmcnt(" #N ")" ::: "memory")
#define WAITLG()  asm volatile("s_waitcnt lgkmcnt(0)" ::: "memory")

__device__ __forceinline__ unsigned short f2bf(float f) {
    union { float f; unsigned int u; } v; v.f = f;
    unsigned int u = v.u;
    return (unsigned short)((u + 0x7FFFu + ((u >> 16) & 1u)) >> 16);  // RTNE
}
__device__ __forceinline__ float silu_f(float v) {
    float e = __expf(-v);
    return v * __builtin_amdgcn_rcpf(1.0f + e);
}

// ---- prep: bf16 B^T layouts in workspace ---------------------------------
// ws (ushort):  W12t [512][640]   (n-major; k<128 = W1[k][n], else W2[k-128][n])
//               tvec  [512] f32   (W1's t-row, k=128)
//               W3t  [128][512]   (W3t[c][k] = W3[k][c])
__global__ void prep_weights(const float* __restrict__ W1,
                             const float* __restrict__ W2,
                             const float* __restrict__ W3,
                             unsigned short* __restrict__ ws) {
    unsigned short* W12t = ws;
    float*          tvec = (float*)(ws + 512 * W12S);
    unsigned short* W3t  = ws + 512 * W12S + 1024;
    int stride = gridDim.x * blockDim.x;
    int t0 = blockIdx.x * blockDim.x + threadIdx.x;
    for (int i = t0; i < 512 * W12S; i += stride) {
        int n = i / W12S, k = i - n * W12S;
        W12t[i] = (k < 128) ? f2bf(W1[k * 512 + n]) : f2bf(W2[(k - 128) * 512 + n]);
    }
    for (int n = t0; n < 512; n += stride) tvec[n] = W1[128 * 512 + n];
    for (int i = t0; i < 128 * 512; i += stride) {
        int c = i >> 9, k = i & 511;
        W3t[i] = f2bf(W3[k * 128 + c]);
    }
}

// ---- main persistent kernel ----------------------------------------------
// 512 threads = 8 waves. Wave w owns h-cols [w*64,+64) (layers 1/2) and
// output cols [w*16,+16) (layer 3). NO persistent weight registers: all
// three weight matrices stream per eval through one 3-deep 32KB-slot LDS
// ring via global_load_lds (fire-and-forget, counted vmcnt(8), no in-loop
// barriers; each wave stages exactly what it consumes). 24 chunks/eval:
// a0..a3 (W1), b0..b15 (W2), c0..c3 (W3 superchunks). Slot schedule cycles
// cleanly across layer barriers and evals (verified: slot(i)=i%3 in L1,
// (j+1)%3 in L2, (k+2)%3 in L3; refill = chunk needed 3 iters later).
// Register demand ~90 -> fits the 128-VGPR allocation with NO scratch
// (previous rounds spilled 200-reg demand -> scratch storms = the 17us/eval).
__global__ __launch_bounds__(512, 2)
void ode_kernel(
    const float* __restrict__ x_in,
    const float* __restrict__ b1,
    const float* __restrict__ b2,
    const float* __restrict__ b3,
    const unsigned short* __restrict__ ws,
    float* __restrict__ traj) {

    __shared__ __attribute__((aligned(16))) unsigned short h1buf[RB * H1S];  // 16,640 B
    __shared__ __attribute__((aligned(16))) unsigned short h2buf[RB * H2S];  // 16,640 B
    __shared__ __attribute__((aligned(16))) unsigned short abuf[RB * ABS];   //  4,352 B
    __shared__ __attribute__((aligned(16))) float outbuf[RB * OUTS];         //  8,448 B
    __shared__ __attribute__((aligned(16))) unsigned short w2c[3 * 16384];   // 98,304 B

    const unsigned short* W12t = ws;
    const float*          tvec = (const float*)(ws + 512 * W12S);
    const unsigned short* W3t  = ws + 512 * W12S + 1024;

    const int tid  = threadIdx.x;
    const int wave = tid >> 6;          // 0..7
    const int lane = tid & 63;
    const int l15  = lane & 15;
    const int q    = lane >> 4;         // quad 0..3
    const int rowbase = blockIdx.x * RB;
    const int phase = (blockIdx.x >> 3) & 15;   // per-XCD desync
    const int p3 = phase & 3;
#define CC(c)  (((c) + phase) & 15)
#define CA(c)  (((c) + p3) & 3)

    // ---- biases + t-column (persistent, tiny) ----
    const int ncol = wave * 64 + l15;   // layer1/2 n-col base for nt=0
    float b1v[4], t1v[4], b2v[4];
#pragma unroll
    for (int nt = 0; nt < 4; ++nt) {
        b1v[nt] = b1[ncol + nt * 16];
        t1v[nt] = tvec[ncol + nt * 16];
        b2v[nt] = b2[ncol + nt * 16];
    }
    const int cown = wave * 16 + l15;   // layer-3 output column
    const float b3v = b3[cown];

    // ---- ring staging geometry -----------------------------------------
    // W12 chunks: 512 rows x 64 B k-slice; wave w stages rows [w*64,+64)
    // as 4 loads of 16 rows (64 lanes x 16 B, linear LDS dest).
    // Swizzle (both sides): LDS (row n, slot s) holds global part s^m(n),
    // m(n) = (n&3)^((n>>2)&3) — depends only on n&15, so local==absolute.
    const int mlan = ((lane >> 2) & 3) ^ ((lane >> 4) & 3);
    const unsigned short* sb12[4];
    {
        const int partp = (lane & 3) ^ mlan;
#pragma unroll
        for (int j = 0; j < 4; ++j) {
            const int n = wave * 64 + j * 16 + (lane >> 2);
            sb12[j] = W12t + (size_t)n * W12S + partp * 8;
        }
    }
    // W3 superchunk sc: k in [sc*128,+128), load j = k-slice [sc*128+j*32,+32),
    // 16 cols x 32 k per load; wave w stages cols [w*16,+16).
    const unsigned short* sb3;
    {
        const int col = wave * 16 + (lane >> 2);
        const int partp = (lane & 3) ^ mlan;
        sb3 = W3t + (size_t)col * 512 + partp * 8;
    }
    const int m15 = (l15 & 3) ^ ((l15 >> 2) & 3);
    int roff[4];   // L1/L2 consumer offsets (ushort, within slot)
#pragma unroll
    for (int nt = 0; nt < 4; ++nt)
        roff[nt] = (wave * 64 + nt * 16 + l15) * 32 + (q ^ m15) * 8;
    const int roff3 = wave * 2048 + l15 * 32 + (q ^ m15) * 8;  // + j*512 per j

#define ISSUE12(koff, slot) do {                                             \
    _Pragma("unroll")                                                        \
    for (int j_ = 0; j_ < 4; ++j_) {                                         \
        const unsigned short* srcp_ = sb12[j_] + (koff);                     \
        unsigned short* dstp_ = w2c + (slot) * 16384 + (wave * 4 + j_) * 512;\
        __builtin_amdgcn_global_load_lds((const glob_void*)srcp_,            \
                                         (lds_void*)dstp_, 16, 0, 0);        \
    }                                                                        \
} while (0)
#define ISSUE3(sc, slot) do {                                                \
    _Pragma("unroll")                                                        \
    for (int j_ = 0; j_ < 4; ++j_) {                                         \
        const unsigned short* srcp_ = sb3 + (sc) * 128 + j_ * 32;            \
        unsigned short* dstp_ = w2c + (slot) * 16384 + (wave * 4 + j_) * 512;\
        __builtin_amdgcn_global_load_lds((const glob_void*)srcp_,            \
                                         (lds_void*)dstp_, 16, 0, 0);        \
    }                                                                        \
} while (0)

    float xreg[4];    // RK4 state: row q*4+i, col cown
    float accreg[4];

    // phase 0: pre-issue a-chunks CA(0..2) into slots 0,1,2; load x
    ISSUE12(CA(0) * 32, 0); ISSUE12(CA(1) * 32, 1); ISSUE12(CA(2) * 32, 2);
#pragma unroll
    for (int i = 0; i < 4; ++i) {
        int r = q * 4 + i;
        float v = x_in[(rowbase + r) * F + cown];
        xreg[i] = v;
        __builtin_nontemporal_store(v, traj + (rowbase + r) * F + cown);
        abuf[r * ABS + cown] = f2bf(v);
    }
    __syncthreads();   // drain lands the pre-issued chunks

#pragma unroll 1
    for (int s = 0; s < NSTEPS - 1; ++s) {
        const float t0  = (float)s * (1.0f / 99.0f);
        const float tn  = (float)(s + 1) * (1.0f / 99.0f);
        const float dt  = tn - t0;
        const float hlf = 0.5f * dt;
        const float c16 = dt * (1.0f / 6.0f);
        const float c13 = dt * (1.0f / 3.0f);

#pragma unroll 1
        for (int e = 0; e < 4; ++e) {
            const float te = (e == 0) ? t0 : ((e == 3) ? tn : (t0 + hlf));

            // ---- layer 1: h1 = silu([x,t]@W1 + b1), ring chunks a0..a3 ----
            {
                f32x4 acc1[4];
#pragma unroll
                for (int nt = 0; nt < 4; ++nt) acc1[nt] = (f32x4){0.f, 0.f, 0.f, 0.f};
#pragma unroll 4
                for (int i = 0; i < 4; ++i) {
                    const int slot = i % 3;
                    if (i == 3) WAITVM(8);
                    __builtin_amdgcn_sched_barrier(0);
                    const int ka = CA(i);
                    short8 af  = *(const short8*)(abuf + l15 * ABS + ka * 32 + q * 8);
                    short8 bf0 = *(const short8*)(w2c + slot * 16384 + roff[0]);
                    short8 bf1 = *(const short8*)(w2c + slot * 16384 + roff[1]);
                    short8 bf2 = *(const short8*)(w2c + slot * 16384 + roff[2]);
                    short8 bf3 = *(const short8*)(w2c + slot * 16384 + roff[3]);
                    acc1[0] = __builtin_amdgcn_mfma_f32_16x16x32_bf16(af, bf0, acc1[0], 0, 0, 0);
                    acc1[1] = __builtin_amdgcn_mfma_f32_16x16x32_bf16(af, bf1, acc1[1], 0, 0, 0);
                    acc1[2] = __builtin_amdgcn_mfma_f32_16x16x32_bf16(af, bf2, acc1[2], 0, 0, 0);
                    acc1[3] = __builtin_amdgcn_mfma_f32_16x16x32_bf16(af, bf3, acc1[3], 0, 0, 0);
                    WAITLG();
                    __builtin_amdgcn_sched_barrier(0);
                    if (i == 0) ISSUE12(CA(3) * 32, slot);              // a3
                    else        ISSUE12(128 + CC(i - 1) * 32, slot);    // b0..b2
                }
#pragma unroll
                for (int nt = 0; nt < 4; ++nt) {
                    const float bb = b1v[nt] + te * t1v[nt];
                    const int n = ncol + nt * 16;
#pragma unroll
                    for (int i = 0; i < 4; ++i)
                        h1buf[(q * 4 + i) * H1S + n] = f2bf(silu_f(acc1[nt][i] + bb));
                }
            }
            __syncthreads();   // h1 ready; drain lands b0..b2

            // ---- layer 2: h2 = silu(h1@W2 + b2), ring chunks b0..b15 ----
            {
                f32x4 acc0 = {0.f, 0.f, 0.f, 0.f};
                f32x4 acc1 = {0.f, 0.f, 0.f, 0.f};
                f32x4 acc2 = {0.f, 0.f, 0.f, 0.f};
                f32x4 acc3 = {0.f, 0.f, 0.f, 0.f};
#pragma unroll 16
                for (int j = 0; j < 16; ++j) {
                    const int slot = (j + 1) % 3;
                    if (j >= 3) WAITVM(8);
                    __builtin_amdgcn_sched_barrier(0);
                    const int kb = CC(j);
                    short8 a2  = *(const short8*)(h1buf + l15 * H1S + kb * 32 + q * 8);
                    short8 bf0 = *(const short8*)(w2c + slot * 16384 + roff[0]);
                    short8 bf1 = *(const short8*)(w2c + slot * 16384 + roff[1]);
                    short8 bf2 = *(const short8*)(w2c + slot * 16384 + roff[2]);
                    short8 bf3 = *(const short8*)(w2c + slot * 16384 + roff[3]);
                    acc0 = __builtin_amdgcn_mfma_f32_16x16x32_bf16(a2, bf0, acc0, 0, 0, 0);
                    acc1 = __builtin_amdgcn_mfma_f32_16x16x32_bf16(a2, bf1, acc1, 0, 0, 0);
                    acc2 = __builtin_amdgcn_mfma_f32_16x16x32_bf16(a2, bf2, acc2, 0, 0, 0);
                    acc3 = __builtin_amdgcn_mfma_f32_16x16x32_bf16(a2, bf3, acc3, 0, 0, 0);
                    WAITLG();
                    __builtin_amdgcn_sched_barrier(0);
                    if (j <= 12) ISSUE12(128 + CC(j + 3) * 32, slot);   // b3..b15
                    else         ISSUE3(CA(j - 13), slot);              // c0..c2
                }
                const f32x4 accs[4] = {acc0, acc1, acc2, acc3};
#pragma unroll
                for (int nt = 0; nt < 4; ++nt) {
                    const int n = ncol + nt * 16;
#pragma unroll
                    for (int i = 0; i < 4; ++i)
                        h2buf[(q * 4 + i) * H2S + n] = f2bf(silu_f(accs[nt][i] + b2v[nt]));
                }
            }
            __syncthreads();   // h2 ready; drain lands c0..c2

            // ---- layer 3: k = h2@W3 + b3, ring superchunks c0..c3 ----
            {
                f32x4 a3 = {0.f, 0.f, 0.f, 0.f};
#pragma unroll 4
                for (int k = 0; k < 4; ++k) {
                    const int slot = (k + 2) % 3;
                    if (k == 3) WAITVM(8);
                    __builtin_amdgcn_sched_barrier(0);
                    const int sc = CA(k);
#pragma unroll
                    for (int j = 0; j < 4; ++j) {
                        short8 af = *(const short8*)(h2buf + l15 * H2S + (sc * 4 + j) * 32 + q * 8);
                        short8 wf = *(const short8*)(w2c + slot * 16384 + roff3 + j * 512);
                        a3 = __builtin_amdgcn_mfma_f32_16x16x32_bf16(af, wf, a3, 0, 0, 0);
                    }
                    WAITLG();
                    __builtin_amdgcn_sched_barrier(0);
                    if (k == 0) ISSUE3(CA(3), slot);                    // c3
                    else        ISSUE12(CA(k - 1) * 32, slot);          // next-eval a0..a2
                }
#pragma unroll
                for (int i = 0; i < 4; ++i) {
                    const int r = q * 4 + i;
                    const float kv = a3[i] + b3v;
                    if (e == 0) {
                        accreg[i] = xreg[i] + c16 * kv;
                        abuf[r * ABS + cown] = f2bf(xreg[i] + hlf * kv);
                    } else if (e == 1) {
                        accreg[i] += c13 * kv;
                        abuf[r * ABS + cown] = f2bf(xreg[i] + hlf * kv);
                    } else if (e == 2) {
                        accreg[i] += c13 * kv;
                        abuf[r * ABS + cown] = f2bf(xreg[i] + dt * kv);
                    } else {
                        float xn = accreg[i] + c16 * kv;
                        xreg[i] = xn;
                        abuf[r * ABS + cown] = f2bf(xn);
                        outbuf[r * OUTS + cown] = xn;   // f32 tile for coalesced NT store
                    }
                }
            }
            __syncthreads();

            // ---- non-temporal coalesced traj store, f32x4/thread ----
            if (e == 3) {
                const int row = tid >> 5;          // 16 rows x 32 threads
                const int c4  = (tid & 31) * 4;
                f32x4 v = *(const f32x4*)(outbuf + row * OUTS + c4);
                __builtin_nontemporal_store(v,
                    (f32x4*)(traj + (size_t)(s + 1) * (4096 * F)
                                  + (size_t)(rowbase + row) * F + c4));
            }
        }
    }
    // drain all outstanding VMEM (incl. LDS-targeted DMA) before exit
    asm volatile("s_waitcnt vmcnt(0)" ::: "memory");
#undef ISSUE12
#undef ISSUE3
#undef CC
#undef CA
}

extern "C" void kernel_launch(void* const* d_in, const int* in_sizes, int n_in,
                              void* d_out, int out_size, void* d_ws, size_t ws_size,
                              hipStream_t stream) {
    const float* x  = (const float*)d_in[0];
    const float* W1 = (const float*)d_in[1];
    const float* b1 = (const float*)d_in[2];
    const float* W2 = (const float*)d_in[3];
    const float* b2 = (const float*)d_in[4];
    const float* W3 = (const float*)d_in[5];
    const float* b3 = (const float*)d_in[6];
    // d_in[7] = n_steps (fixed at 100 per reference; hardcoded)

    unsigned short* wt = (unsigned short*)d_ws;  // needs 788,480 B
    float* traj = (float*)d_out;

    prep_weights<<<256, 256, 0, stream>>>(W1, W2, W3, wt);
    ode_kernel<<<4096 / RB, 512, 0, stream>>>(x, b1, b2, b3, wt, traj);
}